// Round 8
// baseline (1464.895 us; speedup 1.0000x reference)
//
#include <hip/hip_runtime.h>

#define NPTS 8192
#define NB 4
#define CH 64
#define KNN 16

__device__ __forceinline__ float bf2f(unsigned short u) {
    return __uint_as_float(((unsigned)u) << 16);
}
__device__ __forceinline__ unsigned short f2bf(float f) {
    unsigned u = __float_as_uint(f);
    u += 0x7fffu + ((u >> 16) & 1u);
    return (unsigned short)(u >> 16);
}

// sorted insertion of (d,i), strict < : lower-index-first on ties (ascending scan)
#define INSERT16(cd, ci, dist, idx)                         \
    {                                                       \
        float _cd = (cd); int _ci = (ci);                   \
        _Pragma("unroll")                                   \
        for (int m = 0; m < KNN; ++m) {                     \
            const bool sw = _cd < dist[m];                  \
            const float td = sw ? dist[m] : _cd;            \
            const int   ti = sw ? idx[m] : _ci;             \
            dist[m] = sw ? _cd : dist[m];                   \
            idx[m]  = sw ? _ci : idx[m];                    \
            _cd = td; _ci = ti;                             \
        }                                                   \
    }

// lexicographic (d,i) compare: true if (dB,iB) < (dA,iA)
__device__ __forceinline__ bool lex_lt(float dB, int iB, float dA, int iA) {
    return (dB < dA) || ((dB == dA) && (iB < iA));
}

// xor-butterfly min within 32-lane halves via ds_swizzle (literal masks required)
__device__ __forceinline__ float swz_min(float x, float y) { return fminf(x, y); }
__device__ __forceinline__ float half_min32(float x) {
    float o;
    o = __uint_as_float((unsigned)__builtin_amdgcn_ds_swizzle(__float_as_uint(x), 0x041F)); // xor 1
    x = fminf(x, o);
    o = __uint_as_float((unsigned)__builtin_amdgcn_ds_swizzle(__float_as_uint(x), 0x081F)); // xor 2
    x = fminf(x, o);
    o = __uint_as_float((unsigned)__builtin_amdgcn_ds_swizzle(__float_as_uint(x), 0x101F)); // xor 4
    x = fminf(x, o);
    o = __uint_as_float((unsigned)__builtin_amdgcn_ds_swizzle(__float_as_uint(x), 0x201F)); // xor 8
    x = fminf(x, o);
    o = __uint_as_float((unsigned)__builtin_amdgcn_ds_swizzle(__float_as_uint(x), 0x401F)); // xor 16
    x = fminf(x, o);
    return x;
}

// ---------------- Kernel 1: wave-per-query KNN, thresholded insert ----------------
// 4 waves/block = 4 queries. Lane l scans candidates j = t*64+l with a per-lane
// sorted top-16, but insertions are gated by T = half-wave min of lane 16ths
// (T >= global 16th at all times -> no true neighbor is ever missed; strict <
// preserves top_k's lower-index tie-break). 6-level LDS butterfly merge (proven
// round 5) produces the exact global top-16.
__global__ __launch_bounds__(256) void knn_wave_kernel(const float* __restrict__ pts,
                                                       int* __restrict__ idx_out) {
    __shared__ float s_d[4][KNN][64];
    __shared__ int   s_i[4][KNN][64];

    const int lane = threadIdx.x & 63;
    const int w    = threadIdx.x >> 6;
    const int q = blockIdx.x * 4 + w;           // 0..32767
    const int b = q >> 13;
    const int n = q & (NPTS - 1);
    const float* pb = pts + (size_t)b * NPTS * 3;

    const float px = pb[n * 3 + 0];
    const float py = pb[n * 3 + 1];
    const float pz = pb[n * 3 + 2];
    const float sqi = (px * px + py * py) + pz * pz;

    float dist[KNN];
    int   idx[KNN];
#pragma unroll
    for (int m = 0; m < KNN; ++m) { dist[m] = 3.4e38f; idx[m] = 0; }

    float T = 3.4e38f;   // admission threshold; always >= global 16th-so-far

#pragma unroll 4
    for (int t = 0; t < NPTS / 64; ++t) {
        const int c = t * 64 + lane;
        const float x = pb[c * 3 + 0];
        const float y = pb[c * 3 + 1];
        const float z = pb[c * 3 + 2];
        const float sqj = (x * x + y * y) + z * z;
        float dot = px * x;
        dot = fmaf(py, y, dot);
        dot = fmaf(pz, z, dot);
        // d = (sq_i + sq_j) - 2*dot ; 2*dot exact so fma == separate rounding
        const float d = fmaf(dot, -2.0f, sqi + sqj);
        const bool trig = d < T;
        if (__any(trig)) {
            if (trig) INSERT16(d, c, dist, idx);   // no-op for non-trig lanes anyway
            T = half_min32(dist[15]);              // tighten (stale-large is safe)
        }
    }

    // butterfly merge via LDS: after 6 levels every lane holds the global top-16.
#pragma unroll
    for (int stride = 1; stride < 64; stride <<= 1) {
#pragma unroll
        for (int m = 0; m < KNN; ++m) {
            s_d[w][m][lane] = dist[m];
            s_i[w][m][lane] = idx[m];
        }
        __builtin_amdgcn_wave_barrier();   // pin write-before-read scheduling
        const int p = lane ^ stride;
        float bd[KNN]; int bi[KNN];
#pragma unroll
        for (int m = 0; m < KNN; ++m) {
            bd[m] = s_d[w][m][p];
            bi[m] = s_i[w][m][p];
        }
        __builtin_amdgcn_wave_barrier();   // pin read-before-next-level-write
        // min-merge with partner's reversed list: dist[m] = lexmin(A[m], B[15-m])
#pragma unroll
        for (int m = 0; m < KNN; ++m) {
            const float db = bd[15 - m];
            const int   ib = bi[15 - m];
            const bool bw = lex_lt(db, ib, dist[m], idx[m]);
            dist[m] = bw ? db : dist[m];
            idx[m]  = bw ? ib : idx[m];
        }
        // bitonic clean: stages 8,4,2,1 ascending
#pragma unroll
        for (int s = 8; s >= 1; s >>= 1) {
#pragma unroll
            for (int m = 0; m < KNN; ++m) {
                if ((m & s) == 0 && (m + s) < KNN) {
                    const float dA = dist[m], dB = dist[m + s];
                    const int   iA = idx[m],  iB = idx[m + s];
                    const bool sw = lex_lt(dB, iB, dA, iA);
                    dist[m]     = sw ? dB : dA;
                    dist[m + s] = sw ? dA : dB;
                    idx[m]      = sw ? iB : iA;
                    idx[m + s]  = sw ? iA : iB;
                }
            }
        }
    }

    if (lane == 0) {
        int* op = idx_out + (size_t)q * KNN;
#pragma unroll
        for (int m = 0; m < KNN; ++m) op[m] = idx[m];
    }
}

// ---------------- Kernel 2: gather + 3 MLPs + max over k (round-2 proven) ----------
__global__ __launch_bounds__(256) void agg_kernel(
    const float* __restrict__ pts,
    const float* __restrict__ feat,
    const float* __restrict__ w_geom,
    const float* __restrict__ g1, const float* __restrict__ b1,
    const float* __restrict__ m1, const float* __restrict__ v1,
    const float* __restrict__ w_sem,
    const float* __restrict__ g2, const float* __restrict__ b2,
    const float* __restrict__ m2, const float* __restrict__ v2,
    const float* __restrict__ w_fuse,
    const float* __restrict__ g3, const float* __restrict__ b3,
    const float* __restrict__ m3, const float* __restrict__ v3,
    const int* __restrict__ knn_idx,
    float* __restrict__ outp) {

    __shared__ alignas(16) unsigned short s_wsem[32][64][4];
    __shared__ alignas(16) unsigned short s_wfuse[32][64][4];
    __shared__ float s_wgeomT[6][64];
    __shared__ float s_s1[64], s_b1[64], s_s2[64], s_b2[64], s_s3[64], s_b3[64];
    __shared__ alignas(16) float s_ctrf[64];
    __shared__ float s_ctrp[4];
    __shared__ int   s_nidx[16];
    __shared__ float s_gdel[16][4];
    __shared__ alignas(16) float s_sdelta[16][64];
    __shared__ alignas(16) float s_mid[16][128];
    __shared__ float s_pmax[4][64];

    const int tid = threadIdx.x;

    for (int e = tid; e < 64 * 128; e += 256) {
        const int o = e >> 7, c = e & 127;
        s_wsem [c >> 2][o][c & 3] = f2bf(w_sem[e]);
        s_wfuse[c >> 2][o][c & 3] = f2bf(w_fuse[e]);
    }
    for (int e = tid; e < 64 * 6; e += 256) {
        const int o = e / 6, c = e - o * 6;
        s_wgeomT[c][o] = w_geom[e];
    }
    if (tid < 64) {
        float s;
        s = g1[tid] / sqrtf(v1[tid] + 1e-5f);
        s_s1[tid] = s; s_b1[tid] = b1[tid] - m1[tid] * s;
        s = g2[tid] / sqrtf(v2[tid] + 1e-5f);
        s_s2[tid] = s; s_b2[tid] = b2[tid] - m2[tid] * s;
        s = g3[tid] / sqrtf(v3[tid] + 1e-5f);
        s_s3[tid] = s; s_b3[tid] = b3[tid] - m3[tid] * s;
    }
    __syncthreads();

    const int o = tid & 63, kg = tid >> 6;

    for (int p = 0; p < 16; ++p) {
        const int pv = blockIdx.x * 16 + p;
        const int b = pv >> 13, n = pv & (NPTS - 1);
        const long pbase = (long)b * NPTS + n;

        if (tid < 16) s_nidx[tid] = knn_idx[pbase * KNN + tid];
        if (tid < 64) s_ctrf[tid] = feat[pbase * CH + tid];
        if (tid < 3)  s_ctrp[tid] = pts[pbase * 3 + tid];
        __syncthreads();

#pragma unroll
        for (int ki = 0; ki < 4; ++ki) {
            const int k = kg * 4 + ki;
            const long nb = (long)b * NPTS + s_nidx[k];
            s_sdelta[k][o] = feat[nb * CH + o] - s_ctrf[o];
        }
        if (tid < 16) {
            const long nb = (long)b * NPTS + s_nidx[tid];
            s_gdel[tid][0] = pts[nb * 3 + 0] - s_ctrp[0];
            s_gdel[tid][1] = pts[nb * 3 + 1] - s_ctrp[1];
            s_gdel[tid][2] = pts[nb * 3 + 2] - s_ctrp[2];
        }
        __syncthreads();

        float accc = 0.f;
#pragma unroll
        for (int qd = 0; qd < 16; ++qd) {
            const ushort4 w = *(const ushort4*)&s_wsem[qd][o][0];
            const float4 cv = *(const float4*)&s_ctrf[qd * 4];
            accc = fmaf(cv.x, bf2f(w.x), accc);
            accc = fmaf(cv.y, bf2f(w.y), accc);
            accc = fmaf(cv.z, bf2f(w.z), accc);
            accc = fmaf(cv.w, bf2f(w.w), accc);
        }
        float cg = s_ctrp[0] * s_wgeomT[0][o];
        cg = fmaf(s_ctrp[1], s_wgeomT[1][o], cg);
        cg = fmaf(s_ctrp[2], s_wgeomT[2][o], cg);

        const float s1o = s_s1[o], b1o = s_b1[o];
        const float s2o = s_s2[o], b2o = s_b2[o];

#pragma unroll
        for (int ki = 0; ki < 4; ++ki) {
            const int k = kg * 4 + ki;
            float g = cg;
            g = fmaf(s_gdel[k][0], s_wgeomT[3][o], g);
            g = fmaf(s_gdel[k][1], s_wgeomT[4][o], g);
            g = fmaf(s_gdel[k][2], s_wgeomT[5][o], g);
            const float gf = fmaxf(fmaf(g, s1o, b1o), 0.f);

            float a = accc;
#pragma unroll
            for (int qd = 0; qd < 16; ++qd) {
                const ushort4 w = *(const ushort4*)&s_wsem[16 + qd][o][0];
                const float4 dv = *(const float4*)&s_sdelta[k][qd * 4];
                a = fmaf(dv.x, bf2f(w.x), a);
                a = fmaf(dv.y, bf2f(w.y), a);
                a = fmaf(dv.z, bf2f(w.z), a);
                a = fmaf(dv.w, bf2f(w.w), a);
            }
            const float sf = fmaxf(fmaf(a, s2o, b2o), 0.f);
            s_mid[k][o] = gf;
            s_mid[k][64 + o] = sf;
        }
        __syncthreads();

        const float s3o = s_s3[o], b3o = s_b3[o];
        float fmx = 0.f;
#pragma unroll
        for (int ki = 0; ki < 4; ++ki) {
            const int k = kg * 4 + ki;
            float a = 0.f;
#pragma unroll
            for (int qd = 0; qd < 32; ++qd) {
                const ushort4 w = *(const ushort4*)&s_wfuse[qd][o][0];
                const float4 mv = *(const float4*)&s_mid[k][qd * 4];
                a = fmaf(mv.x, bf2f(w.x), a);
                a = fmaf(mv.y, bf2f(w.y), a);
                a = fmaf(mv.z, bf2f(w.z), a);
                a = fmaf(mv.w, bf2f(w.w), a);
            }
            const float fu = fmaxf(fmaf(a, s3o, b3o), 0.f);
            fmx = fmaxf(fmx, fu);
        }
        s_pmax[kg][o] = fmx;
        __syncthreads();

        if (tid < 64) {
            const float r = fmaxf(fmaxf(s_pmax[0][tid], s_pmax[1][tid]),
                                  fmaxf(s_pmax[2][tid], s_pmax[3][tid]));
            outp[pbase * CH + tid] = r;
        }
        __syncthreads();
    }
}

extern "C" void kernel_launch(void* const* d_in, const int* in_sizes, int n_in,
                              void* d_out, int out_size, void* d_ws, size_t ws_size,
                              hipStream_t stream) {
    (void)in_sizes; (void)n_in; (void)out_size; (void)ws_size;
    const float* pts    = (const float*)d_in[0];
    const float* feat   = (const float*)d_in[1];
    const float* w_geom = (const float*)d_in[2];
    const float* g1     = (const float*)d_in[3];
    const float* b1     = (const float*)d_in[4];
    const float* m1     = (const float*)d_in[5];
    const float* v1     = (const float*)d_in[6];
    const float* w_sem  = (const float*)d_in[7];
    const float* g2     = (const float*)d_in[8];
    const float* b2     = (const float*)d_in[9];
    const float* m2     = (const float*)d_in[10];
    const float* v2     = (const float*)d_in[11];
    const float* w_fuse = (const float*)d_in[12];
    const float* g3     = (const float*)d_in[13];
    const float* b3     = (const float*)d_in[14];
    const float* m3     = (const float*)d_in[15];
    const float* v3     = (const float*)d_in[16];

    int* idx_final = (int*)d_ws;   // 32768*16*4 = 2 MB

    knn_wave_kernel<<<dim3(NB * NPTS / 4), dim3(256), 0, stream>>>(pts, idx_final);

    agg_kernel<<<dim3(2048), dim3(256), 0, stream>>>(
        pts, feat, w_geom, g1, b1, m1, v1, w_sem, g2, b2, m2, v2,
        w_fuse, g3, b3, m3, v3, idx_final, (float*)d_out);
}

// Round 10
// 1110.080 us; speedup vs baseline: 1.3196x; 1.3196x over previous
//
#include <hip/hip_runtime.h>

#define NPTS 8192
#define NB 4
#define CH 64
#define KNN 16

__device__ __forceinline__ float bf2f(unsigned short u) {
    return __uint_as_float(((unsigned)u) << 16);
}
__device__ __forceinline__ unsigned short f2bf(float f) {
    unsigned u = __float_as_uint(f);
    u += 0x7fffu + ((u >> 16) & 1u);
    return (unsigned short)(u >> 16);
}

// sorted insertion of (d,i), strict < : lower-index-first on ties (ascending scan)
#define INSERT16(cd, ci, dist, idx)                         \
    {                                                       \
        float _cd = (cd); int _ci = (ci);                   \
        _Pragma("unroll")                                   \
        for (int m = 0; m < KNN; ++m) {                     \
            const bool sw = _cd < dist[m];                  \
            const float td = sw ? dist[m] : _cd;            \
            const int   ti = sw ? idx[m] : _ci;             \
            dist[m] = sw ? _cd : dist[m];                   \
            idx[m]  = sw ? _ci : idx[m];                    \
            _cd = td; _ci = ti;                             \
        }                                                   \
    }

// lexicographic (d,i) compare: true if (dB,iB) < (dA,iA)
__device__ __forceinline__ bool lex_lt(float dB, int iB, float dA, int iA) {
    return (dB < dA) || ((dB == dA) && (iB < iA));
}

// squared distance, single definition used by BOTH passes (same rounding path)
__device__ __forceinline__ float dist2(float px, float py, float pz, float sqi,
                                       const float* __restrict__ pb, int c) {
    const float x = pb[c * 3 + 0];
    const float y = pb[c * 3 + 1];
    const float z = pb[c * 3 + 2];
    const float sqj = (x * x + y * y) + z * z;
    float dot = px * x;
    dot = fmaf(py, y, dot);
    dot = fmaf(pz, z, dot);
    // d = (sq_i + sq_j) - 2*dot ; 2*dot exact so fma == separate rounding
    return fmaf(dot, -2.0f, sqi + sqj);
}

// ---------------- Kernel 1: wave-per-query KNN, two-pass threshold ----------------
// Pass A: per-lane min over its 128 candidates -> U = 16th-smallest of the 64 lane
// minima. U >= global 16th distance (16 lanes have min <= U, each witnessed by a
// real candidate). Gate with U + 1e-4 slack (covers any cross-pass ulp noise;
// admission-only, selection stays exact). Pass B: recompute d, compact admitted
// into LDS via ballot+prefix-popcount, distribute in ascending candidate order,
// INSERT16 + proven 6-level lex butterfly -> exact stable top-16.
// All cross-lane LDS exchanges use __syncthreads() (real data barrier).
__global__ __launch_bounds__(256) void knn_wave_kernel(const float* __restrict__ pts,
                                                       int* __restrict__ idx_out) {
    __shared__ float s_d[4][KNN][64];   // butterfly buffer; pass B reuses as survivor dist[1024]
    __shared__ int   s_i[4][KNN][64];   // butterfly buffer; pass B reuses as survivor idx[1024]
    __shared__ float s_mins[4][64];
    __shared__ float s_U[4];

    const int lane = threadIdx.x & 63;
    const int w    = threadIdx.x >> 6;
    const int q = blockIdx.x * 4 + w;           // 0..32767
    const int b = q >> 13;
    const int n = q & (NPTS - 1);
    const float* pb = pts + (size_t)b * NPTS * 3;

    const float px = pb[n * 3 + 0];
    const float py = pb[n * 3 + 1];
    const float pz = pb[n * 3 + 2];
    const float sqi = (px * px + py * py) + pz * pz;

    // ---- Pass A: per-lane min distance ----
    float mn = 3.4e38f;
#pragma unroll 4
    for (int t = 0; t < NPTS / 64; ++t) {
        const float d = dist2(px, py, pz, sqi, pb, t * 64 + lane);
        mn = fminf(mn, d);
    }
    s_mins[w][lane] = mn;
    __syncthreads();
    int rank = 0;
    for (int j = 0; j < 64; ++j) {
        const float v = s_mins[w][j];
        rank += ((v < mn) || (v == mn && j < lane)) ? 1 : 0;
    }
    if (rank == 15) s_U[w] = mn;    // exactly one lane has rank 15
    __syncthreads();
    const float U = s_U[w] + 1e-4f; // admission-only slack; selection stays exact

    // ---- per-lane result lists ----
    float dist[KNN];
    int   idx[KNN];
#pragma unroll
    for (int m = 0; m < KNN; ++m) { dist[m] = 3.4e38f; idx[m] = 0; }

    // ---- Pass B: gated compaction of admitted candidates ----
    float* sb_d = &s_d[w][0][0];   // 1024 floats, wave-private
    int*   sb_i = &s_i[w][0][0];
    int cnt = 0;
#pragma unroll 4
    for (int t = 0; t < NPTS / 64; ++t) {
        const int c = t * 64 + lane;
        const float d = dist2(px, py, pz, sqi, pb, c);
        const bool adm = d <= U;
        const unsigned long long mask = __ballot(adm);
        if (mask) {                              // uniform branch; rare
            const int add = __popcll(mask);
            if (cnt + add <= 1024) {
                if (adm) {
                    const int off = cnt + (int)__popcll(mask & ((1ull << lane) - 1ull));
                    sb_d[off] = d;
                    sb_i[off] = c;
                }
                cnt += add;
            } else if (adm) {
                INSERT16(d, c, dist, idx);       // degenerate-data fallback
            }
        }
    }
    __syncthreads();

    // distribute survivors (buffer ascending in candidate index; per-lane
    // sequence j=lane, lane+64, ... stays ascending -> stable tie-break holds)
    for (int j = lane; j < cnt; j += 64) {
        const float d = sb_d[j];
        const int   c = sb_i[j];
        INSERT16(d, c, dist, idx);
    }
    __syncthreads();   // survivor reads complete before butterfly overwrites

    // ---- butterfly merge via LDS (proven round 5) ----
#pragma unroll
    for (int stride = 1; stride < 64; stride <<= 1) {
#pragma unroll
        for (int m = 0; m < KNN; ++m) {
            s_d[w][m][lane] = dist[m];
            s_i[w][m][lane] = idx[m];
        }
        __syncthreads();
        const int p = lane ^ stride;
        float bd[KNN]; int bi[KNN];
#pragma unroll
        for (int m = 0; m < KNN; ++m) {
            bd[m] = s_d[w][m][p];
            bi[m] = s_i[w][m][p];
        }
        __syncthreads();
#pragma unroll
        for (int m = 0; m < KNN; ++m) {
            const float db = bd[15 - m];
            const int   ib = bi[15 - m];
            const bool bw = lex_lt(db, ib, dist[m], idx[m]);
            dist[m] = bw ? db : dist[m];
            idx[m]  = bw ? ib : idx[m];
        }
#pragma unroll
        for (int s = 8; s >= 1; s >>= 1) {
#pragma unroll
            for (int m = 0; m < KNN; ++m) {
                if ((m & s) == 0 && (m + s) < KNN) {
                    const float dA = dist[m], dB = dist[m + s];
                    const int   iA = idx[m],  iB = idx[m + s];
                    const bool sw = lex_lt(dB, iB, dA, iA);
                    dist[m]     = sw ? dB : dA;
                    dist[m + s] = sw ? dA : dB;
                    idx[m]      = sw ? iB : iA;
                    idx[m + s]  = sw ? iA : iB;
                }
            }
        }
    }

    if (lane == 0) {
        int* op = idx_out + (size_t)q * KNN;
#pragma unroll
        for (int m = 0; m < KNN; ++m) op[m] = idx[m];
    }
}

// ---------------- Kernel 2: gather + 3 MLPs + max over k (round-2 proven) ----------
__global__ __launch_bounds__(256) void agg_kernel(
    const float* __restrict__ pts,
    const float* __restrict__ feat,
    const float* __restrict__ w_geom,
    const float* __restrict__ g1, const float* __restrict__ b1,
    const float* __restrict__ m1, const float* __restrict__ v1,
    const float* __restrict__ w_sem,
    const float* __restrict__ g2, const float* __restrict__ b2,
    const float* __restrict__ m2, const float* __restrict__ v2,
    const float* __restrict__ w_fuse,
    const float* __restrict__ g3, const float* __restrict__ b3,
    const float* __restrict__ m3, const float* __restrict__ v3,
    const int* __restrict__ knn_idx,
    float* __restrict__ outp) {

    __shared__ alignas(16) unsigned short s_wsem[32][64][4];
    __shared__ alignas(16) unsigned short s_wfuse[32][64][4];
    __shared__ float s_wgeomT[6][64];
    __shared__ float s_s1[64], s_b1[64], s_s2[64], s_b2[64], s_s3[64], s_b3[64];
    __shared__ alignas(16) float s_ctrf[64];
    __shared__ float s_ctrp[4];
    __shared__ int   s_nidx[16];
    __shared__ float s_gdel[16][4];
    __shared__ alignas(16) float s_sdelta[16][64];
    __shared__ alignas(16) float s_mid[16][128];
    __shared__ float s_pmax[4][64];

    const int tid = threadIdx.x;

    for (int e = tid; e < 64 * 128; e += 256) {
        const int o = e >> 7, c = e & 127;
        s_wsem [c >> 2][o][c & 3] = f2bf(w_sem[e]);
        s_wfuse[c >> 2][o][c & 3] = f2bf(w_fuse[e]);
    }
    for (int e = tid; e < 64 * 6; e += 256) {
        const int o = e / 6, c = e - o * 6;
        s_wgeomT[c][o] = w_geom[e];
    }
    if (tid < 64) {
        float s;
        s = g1[tid] / sqrtf(v1[tid] + 1e-5f);
        s_s1[tid] = s; s_b1[tid] = b1[tid] - m1[tid] * s;
        s = g2[tid] / sqrtf(v2[tid] + 1e-5f);
        s_s2[tid] = s; s_b2[tid] = b2[tid] - m2[tid] * s;
        s = g3[tid] / sqrtf(v3[tid] + 1e-5f);
        s_s3[tid] = s; s_b3[tid] = b3[tid] - m3[tid] * s;
    }
    __syncthreads();

    const int o = tid & 63, kg = tid >> 6;

    for (int p = 0; p < 16; ++p) {
        const int pv = blockIdx.x * 16 + p;
        const int b = pv >> 13, n = pv & (NPTS - 1);
        const long pbase = (long)b * NPTS + n;

        if (tid < 16) s_nidx[tid] = knn_idx[pbase * KNN + tid];
        if (tid < 64) s_ctrf[tid] = feat[pbase * CH + tid];
        if (tid < 3)  s_ctrp[tid] = pts[pbase * 3 + tid];
        __syncthreads();

#pragma unroll
        for (int ki = 0; ki < 4; ++ki) {
            const int k = kg * 4 + ki;
            const long nb = (long)b * NPTS + s_nidx[k];
            s_sdelta[k][o] = feat[nb * CH + o] - s_ctrf[o];
        }
        if (tid < 16) {
            const long nb = (long)b * NPTS + s_nidx[tid];
            s_gdel[tid][0] = pts[nb * 3 + 0] - s_ctrp[0];
            s_gdel[tid][1] = pts[nb * 3 + 1] - s_ctrp[1];
            s_gdel[tid][2] = pts[nb * 3 + 2] - s_ctrp[2];
        }
        __syncthreads();

        float accc = 0.f;
#pragma unroll
        for (int qd = 0; qd < 16; ++qd) {
            const ushort4 w = *(const ushort4*)&s_wsem[qd][o][0];
            const float4 cv = *(const float4*)&s_ctrf[qd * 4];
            accc = fmaf(cv.x, bf2f(w.x), accc);
            accc = fmaf(cv.y, bf2f(w.y), accc);
            accc = fmaf(cv.z, bf2f(w.z), accc);
            accc = fmaf(cv.w, bf2f(w.w), accc);
        }
        float cg = s_ctrp[0] * s_wgeomT[0][o];
        cg = fmaf(s_ctrp[1], s_wgeomT[1][o], cg);
        cg = fmaf(s_ctrp[2], s_wgeomT[2][o], cg);

        const float s1o = s_s1[o], b1o = s_b1[o];
        const float s2o = s_s2[o], b2o = s_b2[o];

#pragma unroll
        for (int ki = 0; ki < 4; ++ki) {
            const int k = kg * 4 + ki;
            float g = cg;
            g = fmaf(s_gdel[k][0], s_wgeomT[3][o], g);
            g = fmaf(s_gdel[k][1], s_wgeomT[4][o], g);
            g = fmaf(s_gdel[k][2], s_wgeomT[5][o], g);
            const float gf = fmaxf(fmaf(g, s1o, b1o), 0.f);

            float a = accc;
#pragma unroll
            for (int qd = 0; qd < 16; ++qd) {
                const ushort4 w = *(const ushort4*)&s_wsem[16 + qd][o][0];
                const float4 dv = *(const float4*)&s_sdelta[k][qd * 4];
                a = fmaf(dv.x, bf2f(w.x), a);
                a = fmaf(dv.y, bf2f(w.y), a);
                a = fmaf(dv.z, bf2f(w.z), a);
                a = fmaf(dv.w, bf2f(w.w), a);
            }
            const float sf = fmaxf(fmaf(a, s2o, b2o), 0.f);
            s_mid[k][o] = gf;
            s_mid[k][64 + o] = sf;
        }
        __syncthreads();

        const float s3o = s_s3[o], b3o = s_b3[o];
        float fmx = 0.f;
#pragma unroll
        for (int ki = 0; ki < 4; ++ki) {
            const int k = kg * 4 + ki;
            float a = 0.f;
#pragma unroll
            for (int qd = 0; qd < 32; ++qd) {
                const ushort4 w = *(const ushort4*)&s_wfuse[qd][o][0];
                const float4 mv = *(const float4*)&s_mid[k][qd * 4];
                a = fmaf(mv.x, bf2f(w.x), a);
                a = fmaf(mv.y, bf2f(w.y), a);
                a = fmaf(mv.z, bf2f(w.z), a);
                a = fmaf(mv.w, bf2f(w.w), a);
            }
            const float fu = fmaxf(fmaf(a, s3o, b3o), 0.f);
            fmx = fmaxf(fmx, fu);
        }
        s_pmax[kg][o] = fmx;
        __syncthreads();

        if (tid < 64) {
            const float r = fmaxf(fmaxf(s_pmax[0][tid], s_pmax[1][tid]),
                                  fmaxf(s_pmax[2][tid], s_pmax[3][tid]));
            outp[pbase * CH + tid] = r;
        }
        __syncthreads();
    }
}

extern "C" void kernel_launch(void* const* d_in, const int* in_sizes, int n_in,
                              void* d_out, int out_size, void* d_ws, size_t ws_size,
                              hipStream_t stream) {
    (void)in_sizes; (void)n_in; (void)out_size; (void)ws_size;
    const float* pts    = (const float*)d_in[0];
    const float* feat   = (const float*)d_in[1];
    const float* w_geom = (const float*)d_in[2];
    const float* g1     = (const float*)d_in[3];
    const float* b1     = (const float*)d_in[4];
    const float* m1     = (const float*)d_in[5];
    const float* v1     = (const float*)d_in[6];
    const float* w_sem  = (const float*)d_in[7];
    const float* g2     = (const float*)d_in[8];
    const float* b2     = (const float*)d_in[9];
    const float* m2     = (const float*)d_in[10];
    const float* v2     = (const float*)d_in[11];
    const float* w_fuse = (const float*)d_in[12];
    const float* g3     = (const float*)d_in[13];
    const float* b3     = (const float*)d_in[14];
    const float* m3     = (const float*)d_in[15];
    const float* v3     = (const float*)d_in[16];

    int* idx_final = (int*)d_ws;   // 32768*16*4 = 2 MB

    knn_wave_kernel<<<dim3(NB * NPTS / 4), dim3(256), 0, stream>>>(pts, idx_final);

    agg_kernel<<<dim3(2048), dim3(256), 0, stream>>>(
        pts, feat, w_geom, g1, b1, m1, v1, w_sem, g2, b2, m2, v2,
        w_fuse, g3, b3, m3, v3, idx_final, (float*)d_out);
}

// Round 12
// 611.669 us; speedup vs baseline: 2.3949x; 1.8148x over previous
//
#include <hip/hip_runtime.h>

#define NPTS 8192
#define NB 4
#define CH 64
#define KNN 16

using bf16x8 = __attribute__((ext_vector_type(8))) __bf16;
using us8    = __attribute__((ext_vector_type(8))) unsigned short;
using f32x4  = __attribute__((ext_vector_type(4))) float;

__device__ __forceinline__ float bf2f(unsigned short u) {
    return __uint_as_float(((unsigned)u) << 16);
}
__device__ __forceinline__ unsigned short f2bf(float f) {
    unsigned u = __float_as_uint(f);
    u += 0x7fffu + ((u >> 16) & 1u);
    return (unsigned short)(u >> 16);
}

// split 8 f32 into hi/lo bf16 fragments: x = hi + lo to ~16 extra mantissa bits
__device__ __forceinline__ void split8(const float* x, bf16x8& hi, bf16x8& lo) {
    us8 h, l;
#pragma unroll
    for (int j = 0; j < 8; ++j) {
        const unsigned short hb = f2bf(x[j]);
        h[j] = hb;
        l[j] = f2bf(x[j] - bf2f(hb));
    }
    hi = __builtin_bit_cast(bf16x8, h);
    lo = __builtin_bit_cast(bf16x8, l);
}

// sorted insertion of (d,i), strict < : lower-index-first on ties (ascending scan)
#define INSERT16(cd, ci, dist, idx)                         \
    {                                                       \
        float _cd = (cd); int _ci = (ci);                   \
        _Pragma("unroll")                                   \
        for (int m = 0; m < KNN; ++m) {                     \
            const bool sw = _cd < dist[m];                  \
            const float td = sw ? dist[m] : _cd;            \
            const int   ti = sw ? idx[m] : _ci;             \
            dist[m] = sw ? _cd : dist[m];                   \
            idx[m]  = sw ? _ci : idx[m];                    \
            _cd = td; _ci = ti;                             \
        }                                                   \
    }

__device__ __forceinline__ bool lex_lt(float dB, int iB, float dA, int iA) {
    return (dB < dA) || ((dB == dA) && (iB < iA));
}

__device__ __forceinline__ float dist2(float px, float py, float pz, float sqi,
                                       const float* __restrict__ pb, int c) {
    const float x = pb[c * 3 + 0];
    const float y = pb[c * 3 + 1];
    const float z = pb[c * 3 + 2];
    const float sqj = (x * x + y * y) + z * z;
    float dot = px * x;
    dot = fmaf(py, y, dot);
    dot = fmaf(pz, z, dot);
    return fmaf(dot, -2.0f, sqi + sqj);
}

// ---------------- Kernel 1: wave-per-query KNN, two-pass threshold (round-9 proven) ----
__global__ __launch_bounds__(256) void knn_wave_kernel(const float* __restrict__ pts,
                                                       int* __restrict__ idx_out) {
    __shared__ float s_d[4][KNN][64];
    __shared__ int   s_i[4][KNN][64];
    __shared__ float s_mins[4][64];
    __shared__ float s_U[4];

    const int lane = threadIdx.x & 63;
    const int w    = threadIdx.x >> 6;
    const int q = blockIdx.x * 4 + w;
    const int b = q >> 13;
    const int n = q & (NPTS - 1);
    const float* pb = pts + (size_t)b * NPTS * 3;

    const float px = pb[n * 3 + 0];
    const float py = pb[n * 3 + 1];
    const float pz = pb[n * 3 + 2];
    const float sqi = (px * px + py * py) + pz * pz;

    float mn = 3.4e38f;
#pragma unroll 4
    for (int t = 0; t < NPTS / 64; ++t) {
        const float d = dist2(px, py, pz, sqi, pb, t * 64 + lane);
        mn = fminf(mn, d);
    }
    s_mins[w][lane] = mn;
    __syncthreads();
    int rank = 0;
    for (int j = 0; j < 64; ++j) {
        const float v = s_mins[w][j];
        rank += ((v < mn) || (v == mn && j < lane)) ? 1 : 0;
    }
    if (rank == 15) s_U[w] = mn;
    __syncthreads();
    const float U = s_U[w] + 1e-4f;

    float dist[KNN];
    int   idx[KNN];
#pragma unroll
    for (int m = 0; m < KNN; ++m) { dist[m] = 3.4e38f; idx[m] = 0; }

    float* sb_d = &s_d[w][0][0];
    int*   sb_i = &s_i[w][0][0];
    int cnt = 0;
#pragma unroll 4
    for (int t = 0; t < NPTS / 64; ++t) {
        const int c = t * 64 + lane;
        const float d = dist2(px, py, pz, sqi, pb, c);
        const bool adm = d <= U;
        const unsigned long long mask = __ballot(adm);
        if (mask) {
            const int add = __popcll(mask);
            if (cnt + add <= 1024) {
                if (adm) {
                    const int off = cnt + (int)__popcll(mask & ((1ull << lane) - 1ull));
                    sb_d[off] = d;
                    sb_i[off] = c;
                }
                cnt += add;
            } else if (adm) {
                INSERT16(d, c, dist, idx);
            }
        }
    }
    __syncthreads();

    for (int j = lane; j < cnt; j += 64) {
        const float d = sb_d[j];
        const int   c = sb_i[j];
        INSERT16(d, c, dist, idx);
    }
    __syncthreads();

#pragma unroll
    for (int stride = 1; stride < 64; stride <<= 1) {
#pragma unroll
        for (int m = 0; m < KNN; ++m) {
            s_d[w][m][lane] = dist[m];
            s_i[w][m][lane] = idx[m];
        }
        __syncthreads();
        const int p = lane ^ stride;
        float bd[KNN]; int bi[KNN];
#pragma unroll
        for (int m = 0; m < KNN; ++m) {
            bd[m] = s_d[w][m][p];
            bi[m] = s_i[w][m][p];
        }
        __syncthreads();
#pragma unroll
        for (int m = 0; m < KNN; ++m) {
            const float db = bd[15 - m];
            const int   ib = bi[15 - m];
            const bool bw = lex_lt(db, ib, dist[m], idx[m]);
            dist[m] = bw ? db : dist[m];
            idx[m]  = bw ? ib : idx[m];
        }
#pragma unroll
        for (int s = 8; s >= 1; s >>= 1) {
#pragma unroll
            for (int m = 0; m < KNN; ++m) {
                if ((m & s) == 0 && (m + s) < KNN) {
                    const float dA = dist[m], dB = dist[m + s];
                    const int   iA = idx[m],  iB = idx[m + s];
                    const bool sw = lex_lt(dB, iB, dA, iA);
                    dist[m]     = sw ? dB : dA;
                    dist[m + s] = sw ? dA : dB;
                    idx[m]      = sw ? iB : iA;
                    idx[m + s]  = sw ? iA : iB;
                }
            }
        }
    }

    if (lane == 0) {
        int* op = idx_out + (size_t)q * KNN;
#pragma unroll
        for (int m = 0; m < KNN; ++m) op[m] = idx[m];
    }
}

// ---------------- Kernel 2: MFMA agg — one wave per point, hi/lo bf16 ----------------
// sem: [16 x 128] @ [128 x 64] via mfma_f32_16x16x32_bf16 (A rows = [ctr | nbr-ctr]);
// fuse: [16 x 128] @ [128 x 64]. B-fragments pre-staged: B[k][n]=w[o][c],
// o=n0*16+(lane&15), c=kc*32+(lane>>4)*8+j. C/D: col=lane&15, row=(lane>>4)*4+reg.
#define MIDP 132   // s_mid leading-dim pad: 128 -> 132 breaks bank-aligned row stride
__global__ __launch_bounds__(256) void agg_kernel(
    const float* __restrict__ pts,
    const float* __restrict__ feat,
    const float* __restrict__ w_geom,
    const float* __restrict__ g1, const float* __restrict__ b1,
    const float* __restrict__ m1, const float* __restrict__ v1,
    const float* __restrict__ w_sem,
    const float* __restrict__ g2, const float* __restrict__ b2,
    const float* __restrict__ m2, const float* __restrict__ v2,
    const float* __restrict__ w_fuse,
    const float* __restrict__ g3, const float* __restrict__ b3,
    const float* __restrict__ m3, const float* __restrict__ v3,
    const int* __restrict__ knn_idx,
    float* __restrict__ outp) {

    __shared__ alignas(16) unsigned short s_wsemB[8192];    // 16 frags x 64 lanes x 8 bf16
    __shared__ alignas(16) unsigned short s_wfuseB[8192];
    __shared__ float s_wg[6][64];
    __shared__ float s_s1[64], s_b1[64], s_s2[64], s_b2[64], s_s3[64], s_b3[64];
    __shared__ alignas(16) float s_mid[4][16][MIDP];
    __shared__ float s_pm[4][4][64];
    __shared__ alignas(16) float s_ctrf[4][64];
    __shared__ float s_gd[4][16][4];
    __shared__ int   s_nidx[4][16];
    __shared__ float s_ctrp[4][4];

    const int tid = threadIdx.x;
    const int w = tid >> 6, lane = tid & 63;
    const int r = lane & 15, qd = lane >> 4;

    // ---- stage B fragments (weights as bf16, exact operand layout) ----
    for (int e = tid; e < 1024; e += 256) {          // e = (kc*4+n0)*64 + ln
        const int ln = e & 63;
        const int o = ((e >> 6) & 3) * 16 + (ln & 15);
        const int c = (e >> 8) * 32 + (ln >> 4) * 8;
        unsigned short ts[8], tf[8];
#pragma unroll
        for (int j = 0; j < 8; ++j) {
            ts[j] = f2bf(w_sem [o * 128 + c + j]);
            tf[j] = f2bf(w_fuse[o * 128 + c + j]);
        }
        *(uint4*)&s_wsemB [e * 8] = *(uint4*)ts;
        *(uint4*)&s_wfuseB[e * 8] = *(uint4*)tf;
    }
    for (int e = tid; e < 384; e += 256) {
        const int c = e >> 6, o = e & 63;
        s_wg[c][o] = w_geom[o * 6 + c];
    }
    if (tid < 64) {
        float s;
        s = g1[tid] / sqrtf(v1[tid] + 1e-5f);
        s_s1[tid] = s; s_b1[tid] = b1[tid] - m1[tid] * s;
        s = g2[tid] / sqrtf(v2[tid] + 1e-5f);
        s_s2[tid] = s; s_b2[tid] = b2[tid] - m2[tid] * s;
        s = g3[tid] / sqrtf(v3[tid] + 1e-5f);
        s_s3[tid] = s; s_b3[tid] = b3[tid] - m3[tid] * s;
    }
    __syncthreads();

    const f32x4 zero = {0.f, 0.f, 0.f, 0.f};

    for (int i = 0; i < 4; ++i) {
        const int pv = blockIdx.x * 16 + w * 4 + i;
        const int b = pv >> 13, n = pv & (NPTS - 1);
        const long pbase = (long)b * NPTS + n;

        if (lane < 16) s_nidx[w][lane] = knn_idx[pbase * KNN + lane];
        s_ctrf[w][lane] = feat[pbase * CH + lane];
        if (lane < 3) s_ctrp[w][lane] = pts[pbase * 3 + lane];
        __syncthreads();                                       // B1

        if (lane < 16) {
            const long nb = (long)b * NPTS + s_nidx[w][lane];
            s_gd[w][lane][0] = pts[nb * 3 + 0] - s_ctrp[w][0];
            s_gd[w][lane][1] = pts[nb * 3 + 1] - s_ctrp[w][1];
            s_gd[w][lane][2] = pts[nb * 3 + 2] - s_ctrp[w][2];
        }

        // ---- sem A fragments: chunks 0,1 = ctr (rows identical); 2,3 = nbr-ctr ----
        bf16x8 ah[4], al[4];
        {
            float xs[8];
#pragma unroll
            for (int kc = 0; kc < 2; ++kc) {
#pragma unroll
                for (int j = 0; j < 8; ++j) xs[j] = s_ctrf[w][kc * 32 + qd * 8 + j];
                split8(xs, ah[kc], al[kc]);
            }
            const long nb = (long)b * NPTS + s_nidx[w][r];
            const float* fp = feat + nb * CH;
#pragma unroll
            for (int kc = 0; kc < 2; ++kc) {
                const int base = kc * 32 + qd * 8;
                const float4 v0 = *(const float4*)(fp + base);
                const float4 v1 = *(const float4*)(fp + base + 4);
                xs[0] = v0.x - s_ctrf[w][base + 0];
                xs[1] = v0.y - s_ctrf[w][base + 1];
                xs[2] = v0.z - s_ctrf[w][base + 2];
                xs[3] = v0.w - s_ctrf[w][base + 3];
                xs[4] = v1.x - s_ctrf[w][base + 4];
                xs[5] = v1.y - s_ctrf[w][base + 5];
                xs[6] = v1.z - s_ctrf[w][base + 6];
                xs[7] = v1.w - s_ctrf[w][base + 7];
                split8(xs, ah[2 + kc], al[2 + kc]);
            }
        }
        f32x4 acc[4] = {zero, zero, zero, zero};
#pragma unroll
        for (int kc = 0; kc < 4; ++kc) {
#pragma unroll
            for (int n0 = 0; n0 < 4; ++n0) {
                const bf16x8 bw = *(const bf16x8*)&s_wsemB[((kc * 4 + n0) * 64 + lane) * 8];
                acc[n0] = __builtin_amdgcn_mfma_f32_16x16x32_bf16(ah[kc], bw, acc[n0], 0, 0, 0);
                acc[n0] = __builtin_amdgcn_mfma_f32_16x16x32_bf16(al[kc], bw, acc[n0], 0, 0, 0);
            }
        }
        // sem epilogue -> mid[:, 64:128]
#pragma unroll
        for (int n0 = 0; n0 < 4; ++n0) {
            const int nn = n0 * 16 + r;
            const float sv = s_s2[nn], bv = s_b2[nn];
#pragma unroll
            for (int reg = 0; reg < 4; ++reg) {
                s_mid[w][qd * 4 + reg][64 + nn] = fmaxf(fmaf(acc[n0][reg], sv, bv), 0.f);
            }
        }
        __syncthreads();                                       // B2 (s_gd ready)

        // geom (K=6, f32 VALU) -> mid[:, 0:64]
        {
            const int o = lane;
            float cg = s_ctrp[w][0] * s_wg[0][o];
            cg = fmaf(s_ctrp[w][1], s_wg[1][o], cg);
            cg = fmaf(s_ctrp[w][2], s_wg[2][o], cg);
            const float s1o = s_s1[o], b1o = s_b1[o];
#pragma unroll
            for (int r2 = 0; r2 < 16; ++r2) {
                float g = cg;
                g = fmaf(s_gd[w][r2][0], s_wg[3][o], g);
                g = fmaf(s_gd[w][r2][1], s_wg[4][o], g);
                g = fmaf(s_gd[w][r2][2], s_wg[5][o], g);
                s_mid[w][r2][o] = fmaxf(fmaf(g, s1o, b1o), 0.f);
            }
        }
        __syncthreads();                                       // B3 (mid complete)

        // ---- fuse A fragments from mid ----
        bf16x8 fh[4], fl[4];
        {
            float xs[8];
#pragma unroll
            for (int kc = 0; kc < 4; ++kc) {
                const float* mp = &s_mid[w][r][kc * 32 + qd * 8];
#pragma unroll
                for (int j = 0; j < 8; ++j) xs[j] = mp[j];
                split8(xs, fh[kc], fl[kc]);
            }
        }
        f32x4 acc2[4] = {zero, zero, zero, zero};
#pragma unroll
        for (int kc = 0; kc < 4; ++kc) {
#pragma unroll
            for (int n0 = 0; n0 < 4; ++n0) {
                const bf16x8 bw = *(const bf16x8*)&s_wfuseB[((kc * 4 + n0) * 64 + lane) * 8];
                acc2[n0] = __builtin_amdgcn_mfma_f32_16x16x32_bf16(fh[kc], bw, acc2[n0], 0, 0, 0);
                acc2[n0] = __builtin_amdgcn_mfma_f32_16x16x32_bf16(fl[kc], bw, acc2[n0], 0, 0, 0);
            }
        }
        // fuse epilogue: scale/bias/relu + max over this quad's 4 rows
#pragma unroll
        for (int n0 = 0; n0 < 4; ++n0) {
            const int nn = n0 * 16 + r;
            const float sv = s_s3[nn], bv = s_b3[nn];
            float mx = 0.f;   // relu outputs >= 0
#pragma unroll
            for (int reg = 0; reg < 4; ++reg)
                mx = fmaxf(mx, fmaxf(fmaf(acc2[n0][reg], sv, bv), 0.f));
            s_pm[w][qd][nn] = mx;
        }
        __syncthreads();                                       // B4
        {
            const int o = lane;
            const float rv = fmaxf(fmaxf(s_pm[w][0][o], s_pm[w][1][o]),
                                   fmaxf(s_pm[w][2][o], s_pm[w][3][o]));
            outp[pbase * CH + o] = rv;
        }
        __syncthreads();                                       // B5 (WAR across iters)
    }
}

extern "C" void kernel_launch(void* const* d_in, const int* in_sizes, int n_in,
                              void* d_out, int out_size, void* d_ws, size_t ws_size,
                              hipStream_t stream) {
    (void)in_sizes; (void)n_in; (void)out_size; (void)ws_size;
    const float* pts    = (const float*)d_in[0];
    const float* feat   = (const float*)d_in[1];
    const float* w_geom = (const float*)d_in[2];
    const float* g1     = (const float*)d_in[3];
    const float* b1     = (const float*)d_in[4];
    const float* m1     = (const float*)d_in[5];
    const float* v1     = (const float*)d_in[6];
    const float* w_sem  = (const float*)d_in[7];
    const float* g2     = (const float*)d_in[8];
    const float* b2     = (const float*)d_in[9];
    const float* m2     = (const float*)d_in[10];
    const float* v2     = (const float*)d_in[11];
    const float* w_fuse = (const float*)d_in[12];
    const float* g3     = (const float*)d_in[13];
    const float* b3     = (const float*)d_in[14];
    const float* m3     = (const float*)d_in[15];
    const float* v3     = (const float*)d_in[16];

    int* idx_final = (int*)d_ws;   // 32768*16*4 = 2 MB

    knn_wave_kernel<<<dim3(NB * NPTS / 4), dim3(256), 0, stream>>>(pts, idx_final);

    agg_kernel<<<dim3(2048), dim3(256), 0, stream>>>(
        pts, feat, w_geom, g1, b1, m1, v1, w_sem, g2, b2, m2, v2,
        w_fuse, g3, b3, m3, v3, idx_final, (float*)d_out);
}

// Round 13
// 505.639 us; speedup vs baseline: 2.8971x; 1.2097x over previous
//
#include <hip/hip_runtime.h>

#define NPTS 8192
#define NB 4
#define CH 64
#define KNN 16

using bf16x8 = __attribute__((ext_vector_type(8))) __bf16;
using us8    = __attribute__((ext_vector_type(8))) unsigned short;
using f32x4  = __attribute__((ext_vector_type(4))) float;

__device__ __forceinline__ float bf2f(unsigned short u) {
    return __uint_as_float(((unsigned)u) << 16);
}
__device__ __forceinline__ unsigned short f2bf(float f) {
    unsigned u = __float_as_uint(f);
    u += 0x7fffu + ((u >> 16) & 1u);
    return (unsigned short)(u >> 16);
}

// split 8 f32 into hi/lo bf16 fragments: x = hi + lo to ~16 extra mantissa bits
__device__ __forceinline__ void split8(const float* x, bf16x8& hi, bf16x8& lo) {
    us8 h, l;
#pragma unroll
    for (int j = 0; j < 8; ++j) {
        const unsigned short hb = f2bf(x[j]);
        h[j] = hb;
        l[j] = f2bf(x[j] - bf2f(hb));
    }
    hi = __builtin_bit_cast(bf16x8, h);
    lo = __builtin_bit_cast(bf16x8, l);
}

// lexicographic (d,i) compare: true if (dB,iB) < (dA,iA)
__device__ __forceinline__ bool lex_lt(float dB, int iB, float dA, int iA) {
    return (dB < dA) || ((dB == dA) && (iB < iA));
}

// ---------------- Kernel 0: pack points as {x,y,z,sq} (sq formula = reference path) --
__global__ __launch_bounds__(256) void pack_kernel(const float* __restrict__ pts,
                                                   float4* __restrict__ pts4) {
    const int i = blockIdx.x * 256 + threadIdx.x;   // 0..32767
    const float x = pts[i * 3 + 0];
    const float y = pts[i * 3 + 1];
    const float z = pts[i * 3 + 2];
    pts4[i] = make_float4(x, y, z, (x * x + y * y) + z * z);
}

// ---------------- Kernel 1: wave-per-query KNN, two-pass threshold ----------------
// Pass A: per-lane min -> U = 16th-smallest lane-min (+1e-4 slack) >= global 16th
// distance; gating d<=U never drops a true neighbor (r9-proven). Pass B: compact
// admitted candidates (d values bit-identical: same packed formula) into LDS via
// ballot+prefix-popcount. Epilogue: direct lex-(d,idx) rank selection over the
// survivor buffer -> idx_out[rank], identical stable order to lax.top_k.
__global__ __launch_bounds__(256) void knn_wave_kernel(const float4* __restrict__ pts4,
                                                       int* __restrict__ idx_out) {
    __shared__ float s_bd[4][1024];
    __shared__ int   s_bi[4][1024];
    __shared__ float s_mins[4][64];
    __shared__ float s_U[4];

    const int lane = threadIdx.x & 63;
    const int w    = threadIdx.x >> 6;
    const int q = blockIdx.x * 4 + w;           // 0..32767
    const int b = q >> 13;
    const int n = q & (NPTS - 1);
    const float4* pb4 = pts4 + (size_t)b * NPTS;

    const float4 qp = pb4[n];
    const float sqi = qp.w;

    // ---- Pass A: per-lane min distance ----
    float mn = 3.4e38f;
#pragma unroll 8
    for (int t = 0; t < NPTS / 64; ++t) {
        const float4 v = pb4[t * 64 + lane];
        float dot = qp.x * v.x;
        dot = fmaf(qp.y, v.y, dot);
        dot = fmaf(qp.z, v.z, dot);
        const float d = fmaf(dot, -2.0f, sqi + v.w);   // identical rounding to r9 path
        mn = fminf(mn, d);
    }
    s_mins[w][lane] = mn;
    __syncthreads();
    int rank = 0;
    for (int j = 0; j < 64; ++j) {
        const float v = s_mins[w][j];
        rank += ((v < mn) || (v == mn && j < lane)) ? 1 : 0;
    }
    if (rank == 15) s_U[w] = mn;    // exactly one lane has rank 15
    __syncthreads();
    const float U = s_U[w] + 1e-4f; // admission-only slack; selection stays exact

    // ---- Pass B: gated compaction of admitted candidates ----
    int cnt = 0;
#pragma unroll 4
    for (int t = 0; t < NPTS / 64; ++t) {
        const int c = t * 64 + lane;
        const float4 v = pb4[c];
        float dot = qp.x * v.x;
        dot = fmaf(qp.y, v.y, dot);
        dot = fmaf(qp.z, v.z, dot);
        const float d = fmaf(dot, -2.0f, sqi + v.w);
        const bool adm = d <= U;
        const unsigned long long mask = __ballot(adm);
        if (mask) {                              // uniform branch; rare
            const int add = __popcll(mask);
            if (adm) {
                const int off = cnt + (int)__popcll(mask & ((1ull << lane) - 1ull));
                if (off < 1024) {                // cap needs ~1009 exact ties to matter
                    s_bd[w][off] = d;
                    s_bi[w][off] = c;
                }
            }
            cnt = min(cnt + add, 1024);
        }
    }
    __syncthreads();

    // ---- rank selection: survivor j's lex rank among all survivors ----
    // top-16 of union subset buffer; rank<16 <=> in top_k, position = top_k slot.
    for (int j = lane; j < cnt; j += 64) {
        const float dj = s_bd[w][j];
        const int   ij = s_bi[w][j];
        int rk = 0;
        for (int k = 0; k < cnt; ++k) {
            rk += lex_lt(s_bd[w][k], s_bi[w][k], dj, ij) ? 1 : 0;
        }
        if (rk < KNN) idx_out[(size_t)q * KNN + rk] = ij;
    }
}

// ---------------- Kernel 2: MFMA agg — one wave per point, hi/lo bf16 (r11-proven) ----
#define MIDP 132   // s_mid leading-dim pad: 128 -> 132 breaks bank-aligned row stride
__global__ __launch_bounds__(256) void agg_kernel(
    const float* __restrict__ pts,
    const float* __restrict__ feat,
    const float* __restrict__ w_geom,
    const float* __restrict__ g1, const float* __restrict__ b1,
    const float* __restrict__ m1, const float* __restrict__ v1,
    const float* __restrict__ w_sem,
    const float* __restrict__ g2, const float* __restrict__ b2,
    const float* __restrict__ m2, const float* __restrict__ v2,
    const float* __restrict__ w_fuse,
    const float* __restrict__ g3, const float* __restrict__ b3,
    const float* __restrict__ m3, const float* __restrict__ v3,
    const int* __restrict__ knn_idx,
    float* __restrict__ outp) {

    __shared__ alignas(16) unsigned short s_wsemB[8192];    // 16 frags x 64 lanes x 8 bf16
    __shared__ alignas(16) unsigned short s_wfuseB[8192];
    __shared__ float s_wg[6][64];
    __shared__ float s_s1[64], s_b1[64], s_s2[64], s_b2[64], s_s3[64], s_b3[64];
    __shared__ alignas(16) float s_mid[4][16][MIDP];
    __shared__ float s_pm[4][4][64];
    __shared__ alignas(16) float s_ctrf[4][64];
    __shared__ float s_gd[4][16][4];
    __shared__ int   s_nidx[4][16];
    __shared__ float s_ctrp[4][4];

    const int tid = threadIdx.x;
    const int w = tid >> 6, lane = tid & 63;
    const int r = lane & 15, qd = lane >> 4;

    for (int e = tid; e < 1024; e += 256) {          // e = (kc*4+n0)*64 + ln
        const int ln = e & 63;
        const int o = ((e >> 6) & 3) * 16 + (ln & 15);
        const int c = (e >> 8) * 32 + (ln >> 4) * 8;
        unsigned short ts[8], tf[8];
#pragma unroll
        for (int j = 0; j < 8; ++j) {
            ts[j] = f2bf(w_sem [o * 128 + c + j]);
            tf[j] = f2bf(w_fuse[o * 128 + c + j]);
        }
        *(uint4*)&s_wsemB [e * 8] = *(uint4*)ts;
        *(uint4*)&s_wfuseB[e * 8] = *(uint4*)tf;
    }
    for (int e = tid; e < 384; e += 256) {
        const int c = e >> 6, o = e & 63;
        s_wg[c][o] = w_geom[o * 6 + c];
    }
    if (tid < 64) {
        float s;
        s = g1[tid] / sqrtf(v1[tid] + 1e-5f);
        s_s1[tid] = s; s_b1[tid] = b1[tid] - m1[tid] * s;
        s = g2[tid] / sqrtf(v2[tid] + 1e-5f);
        s_s2[tid] = s; s_b2[tid] = b2[tid] - m2[tid] * s;
        s = g3[tid] / sqrtf(v3[tid] + 1e-5f);
        s_s3[tid] = s; s_b3[tid] = b3[tid] - m3[tid] * s;
    }
    __syncthreads();

    const f32x4 zero = {0.f, 0.f, 0.f, 0.f};

    for (int i = 0; i < 4; ++i) {
        const int pv = blockIdx.x * 16 + w * 4 + i;
        const int b = pv >> 13, n = pv & (NPTS - 1);
        const long pbase = (long)b * NPTS + n;

        if (lane < 16) s_nidx[w][lane] = knn_idx[pbase * KNN + lane];
        s_ctrf[w][lane] = feat[pbase * CH + lane];
        if (lane < 3) s_ctrp[w][lane] = pts[pbase * 3 + lane];
        __syncthreads();                                       // B1

        if (lane < 16) {
            const long nb = (long)b * NPTS + s_nidx[w][lane];
            s_gd[w][lane][0] = pts[nb * 3 + 0] - s_ctrp[w][0];
            s_gd[w][lane][1] = pts[nb * 3 + 1] - s_ctrp[w][1];
            s_gd[w][lane][2] = pts[nb * 3 + 2] - s_ctrp[w][2];
        }

        bf16x8 ah[4], al[4];
        {
            float xs[8];
#pragma unroll
            for (int kc = 0; kc < 2; ++kc) {
#pragma unroll
                for (int j = 0; j < 8; ++j) xs[j] = s_ctrf[w][kc * 32 + qd * 8 + j];
                split8(xs, ah[kc], al[kc]);
            }
            const long nb = (long)b * NPTS + s_nidx[w][r];
            const float* fp = feat + nb * CH;
#pragma unroll
            for (int kc = 0; kc < 2; ++kc) {
                const int base = kc * 32 + qd * 8;
                const float4 v0 = *(const float4*)(fp + base);
                const float4 v1 = *(const float4*)(fp + base + 4);
                xs[0] = v0.x - s_ctrf[w][base + 0];
                xs[1] = v0.y - s_ctrf[w][base + 1];
                xs[2] = v0.z - s_ctrf[w][base + 2];
                xs[3] = v0.w - s_ctrf[w][base + 3];
                xs[4] = v1.x - s_ctrf[w][base + 4];
                xs[5] = v1.y - s_ctrf[w][base + 5];
                xs[6] = v1.z - s_ctrf[w][base + 6];
                xs[7] = v1.w - s_ctrf[w][base + 7];
                split8(xs, ah[2 + kc], al[2 + kc]);
            }
        }
        f32x4 acc[4] = {zero, zero, zero, zero};
#pragma unroll
        for (int kc = 0; kc < 4; ++kc) {
#pragma unroll
            for (int n0 = 0; n0 < 4; ++n0) {
                const bf16x8 bw = *(const bf16x8*)&s_wsemB[((kc * 4 + n0) * 64 + lane) * 8];
                acc[n0] = __builtin_amdgcn_mfma_f32_16x16x32_bf16(ah[kc], bw, acc[n0], 0, 0, 0);
                acc[n0] = __builtin_amdgcn_mfma_f32_16x16x32_bf16(al[kc], bw, acc[n0], 0, 0, 0);
            }
        }
#pragma unroll
        for (int n0 = 0; n0 < 4; ++n0) {
            const int nn = n0 * 16 + r;
            const float sv = s_s2[nn], bv = s_b2[nn];
#pragma unroll
            for (int reg = 0; reg < 4; ++reg) {
                s_mid[w][qd * 4 + reg][64 + nn] = fmaxf(fmaf(acc[n0][reg], sv, bv), 0.f);
            }
        }
        __syncthreads();                                       // B2 (s_gd ready)

        {
            const int o = lane;
            float cg = s_ctrp[w][0] * s_wg[0][o];
            cg = fmaf(s_ctrp[w][1], s_wg[1][o], cg);
            cg = fmaf(s_ctrp[w][2], s_wg[2][o], cg);
            const float s1o = s_s1[o], b1o = s_b1[o];
#pragma unroll
            for (int r2 = 0; r2 < 16; ++r2) {
                float g = cg;
                g = fmaf(s_gd[w][r2][0], s_wg[3][o], g);
                g = fmaf(s_gd[w][r2][1], s_wg[4][o], g);
                g = fmaf(s_gd[w][r2][2], s_wg[5][o], g);
                s_mid[w][r2][o] = fmaxf(fmaf(g, s1o, b1o), 0.f);
            }
        }
        __syncthreads();                                       // B3 (mid complete)

        bf16x8 fh[4], fl[4];
        {
            float xs[8];
#pragma unroll
            for (int kc = 0; kc < 4; ++kc) {
                const float* mp = &s_mid[w][r][kc * 32 + qd * 8];
#pragma unroll
                for (int j = 0; j < 8; ++j) xs[j] = mp[j];
                split8(xs, fh[kc], fl[kc]);
            }
        }
        f32x4 acc2[4] = {zero, zero, zero, zero};
#pragma unroll
        for (int kc = 0; kc < 4; ++kc) {
#pragma unroll
            for (int n0 = 0; n0 < 4; ++n0) {
                const bf16x8 bw = *(const bf16x8*)&s_wfuseB[((kc * 4 + n0) * 64 + lane) * 8];
                acc2[n0] = __builtin_amdgcn_mfma_f32_16x16x32_bf16(fh[kc], bw, acc2[n0], 0, 0, 0);
                acc2[n0] = __builtin_amdgcn_mfma_f32_16x16x32_bf16(fl[kc], bw, acc2[n0], 0, 0, 0);
            }
        }
#pragma unroll
        for (int n0 = 0; n0 < 4; ++n0) {
            const int nn = n0 * 16 + r;
            const float sv = s_s3[nn], bv = s_b3[nn];
            float mx = 0.f;   // relu outputs >= 0
#pragma unroll
            for (int reg = 0; reg < 4; ++reg)
                mx = fmaxf(mx, fmaxf(fmaf(acc2[n0][reg], sv, bv), 0.f));
            s_pm[w][qd][nn] = mx;
        }
        __syncthreads();                                       // B4
        {
            const int o = lane;
            const float rv = fmaxf(fmaxf(s_pm[w][0][o], s_pm[w][1][o]),
                                   fmaxf(s_pm[w][2][o], s_pm[w][3][o]));
            outp[pbase * CH + o] = rv;
        }
        __syncthreads();                                       // B5 (WAR across iters)
    }
}

extern "C" void kernel_launch(void* const* d_in, const int* in_sizes, int n_in,
                              void* d_out, int out_size, void* d_ws, size_t ws_size,
                              hipStream_t stream) {
    (void)in_sizes; (void)n_in; (void)out_size; (void)ws_size;
    const float* pts    = (const float*)d_in[0];
    const float* feat   = (const float*)d_in[1];
    const float* w_geom = (const float*)d_in[2];
    const float* g1     = (const float*)d_in[3];
    const float* b1     = (const float*)d_in[4];
    const float* m1     = (const float*)d_in[5];
    const float* v1     = (const float*)d_in[6];
    const float* w_sem  = (const float*)d_in[7];
    const float* g2     = (const float*)d_in[8];
    const float* b2     = (const float*)d_in[9];
    const float* m2     = (const float*)d_in[10];
    const float* v2     = (const float*)d_in[11];
    const float* w_fuse = (const float*)d_in[12];
    const float* g3     = (const float*)d_in[13];
    const float* b3     = (const float*)d_in[14];
    const float* m3     = (const float*)d_in[15];
    const float* v3     = (const float*)d_in[16];

    int*    idx_final = (int*)d_ws;                         // 2 MB @ 0
    float4* pts4      = (float4*)((char*)d_ws + (4ull << 20));  // 512 KB @ 4MB

    pack_kernel<<<dim3(NB * NPTS / 256), dim3(256), 0, stream>>>(pts, pts4);
    knn_wave_kernel<<<dim3(NB * NPTS / 4), dim3(256), 0, stream>>>(pts4, idx_final);

    agg_kernel<<<dim3(2048), dim3(256), 0, stream>>>(
        pts, feat, w_geom, g1, b1, m1, v1, w_sem, g2, b2, m2, v2,
        w_fuse, g3, b3, m3, v3, idx_final, (float*)d_out);
}

// Round 14
// 305.450 us; speedup vs baseline: 4.7959x; 1.6554x over previous
//
#include <hip/hip_runtime.h>

#define NPTS 8192
#define NB 4
#define CH 64
#define KNN 16
#define QPW 4      // queries per wave (register-blocked)
#define CAP 256    // survivor cap per query (expected ~20-40; >=16 guaranteed)

using bf16x8 = __attribute__((ext_vector_type(8))) __bf16;
using us8    = __attribute__((ext_vector_type(8))) unsigned short;
using f32x4  = __attribute__((ext_vector_type(4))) float;

__device__ __forceinline__ float bf2f(unsigned short u) {
    return __uint_as_float(((unsigned)u) << 16);
}
__device__ __forceinline__ unsigned short f2bf(float f) {
    unsigned u = __float_as_uint(f);
    u += 0x7fffu + ((u >> 16) & 1u);
    return (unsigned short)(u >> 16);
}

// split 8 f32 into hi/lo bf16 fragments: x = hi + lo to ~16 extra mantissa bits
__device__ __forceinline__ void split8(const float* x, bf16x8& hi, bf16x8& lo) {
    us8 h, l;
#pragma unroll
    for (int j = 0; j < 8; ++j) {
        const unsigned short hb = f2bf(x[j]);
        h[j] = hb;
        l[j] = f2bf(x[j] - bf2f(hb));
    }
    hi = __builtin_bit_cast(bf16x8, h);
    lo = __builtin_bit_cast(bf16x8, l);
}

// lexicographic (d,i) compare: true if (dB,iB) < (dA,iA)
__device__ __forceinline__ bool lex_lt(float dB, int iB, float dA, int iA) {
    return (dB < dA) || ((dB == dA) && (iB < iA));
}

// ---------------- Kernel 0: pack points as {x,y,z,sq} (sq formula = reference path) --
__global__ __launch_bounds__(256) void pack_kernel(const float* __restrict__ pts,
                                                   float4* __restrict__ pts4) {
    const int i = blockIdx.x * 256 + threadIdx.x;   // 0..32767
    const float x = pts[i * 3 + 0];
    const float y = pts[i * 3 + 1];
    const float z = pts[i * 3 + 2];
    pts4[i] = make_float4(x, y, z, (x * x + y * y) + z * z);
}

// ---------------- Kernel 1: 4-query-per-wave KNN, two-pass threshold ----------------
// Each wave handles 4 consecutive queries of one batch; every candidate float4 load
// is reused 4x in registers (L2 traffic /4 vs r12). Selection logic per query is
// verbatim r12 (proven): U = rank-15 of 64 lane-mins (+1e-4 slack, admission-only),
// ballot+prefix compaction in ascending candidate order, lex-(d,idx) rank epilogue
// == lax.top_k stable order.
__global__ __launch_bounds__(256) void knn_wave_kernel(const float4* __restrict__ pts4,
                                                       int* __restrict__ idx_out) {
    __shared__ float s_bd[16][CAP];
    __shared__ int   s_bi[16][CAP];
    __shared__ float s_mins[16][64];
    __shared__ float s_U[16];

    const int lane = threadIdx.x & 63;
    const int w    = threadIdx.x >> 6;
    const int qbase = (blockIdx.x * 4 + w) * QPW;     // 16 queries per block
    const int b = qbase >> 13;                        // 4 queries share one batch
    const int n0 = qbase & (NPTS - 1);
    const float4* pb4 = pts4 + (size_t)b * NPTS;

    float4 qp[QPW];
#pragma unroll
    for (int qq = 0; qq < QPW; ++qq) qp[qq] = pb4[n0 + qq];

    // ---- Pass A: per-lane min distance, 4 queries ----
    float mn[QPW];
#pragma unroll
    for (int qq = 0; qq < QPW; ++qq) mn[qq] = 3.4e38f;
#pragma unroll 4
    for (int t = 0; t < NPTS / 64; ++t) {
        const float4 v = pb4[t * 64 + lane];
#pragma unroll
        for (int qq = 0; qq < QPW; ++qq) {
            float dot = qp[qq].x * v.x;
            dot = fmaf(qp[qq].y, v.y, dot);
            dot = fmaf(qp[qq].z, v.z, dot);
            const float d = fmaf(dot, -2.0f, qp[qq].w + v.w);  // identical rounding
            mn[qq] = fminf(mn[qq], d);
        }
    }
#pragma unroll
    for (int qq = 0; qq < QPW; ++qq) s_mins[w * QPW + qq][lane] = mn[qq];
    __syncthreads();
#pragma unroll
    for (int qq = 0; qq < QPW; ++qq) {
        const float m = mn[qq];
        int rank = 0;
        for (int j = 0; j < 64; ++j) {
            const float vv = s_mins[w * QPW + qq][j];
            rank += ((vv < m) || (vv == m && j < lane)) ? 1 : 0;
        }
        if (rank == 15) s_U[w * QPW + qq] = m;   // exactly one lane has rank 15
    }
    __syncthreads();
    float U[QPW];
#pragma unroll
    for (int qq = 0; qq < QPW; ++qq) U[qq] = s_U[w * QPW + qq] + 1e-4f;

    // ---- Pass B: gated compaction, 4 queries ----
    int cnt[QPW] = {0, 0, 0, 0};
#pragma unroll 2
    for (int t = 0; t < NPTS / 64; ++t) {
        const int c = t * 64 + lane;
        const float4 v = pb4[c];
#pragma unroll
        for (int qq = 0; qq < QPW; ++qq) {
            float dot = qp[qq].x * v.x;
            dot = fmaf(qp[qq].y, v.y, dot);
            dot = fmaf(qp[qq].z, v.z, dot);
            const float d = fmaf(dot, -2.0f, qp[qq].w + v.w);
            const bool adm = d <= U[qq];
            const unsigned long long mask = __ballot(adm);
            if (mask) {                          // uniform branch; rare per query
                const int add = __popcll(mask);
                if (adm) {
                    const int off = cnt[qq] + (int)__popcll(mask & ((1ull << lane) - 1ull));
                    if (off < CAP) {
                        s_bd[w * QPW + qq][off] = d;
                        s_bi[w * QPW + qq][off] = c;
                    }
                }
                cnt[qq] = min(cnt[qq] + add, CAP);
            }
        }
    }
    __syncthreads();

    // ---- rank selection: survivor j's lex rank among its query's survivors ----
#pragma unroll
    for (int qq = 0; qq < QPW; ++qq) {
        const int qi = w * QPW + qq;
        const int cn = cnt[qq];
        for (int j = lane; j < cn; j += 64) {
            const float dj = s_bd[qi][j];
            const int   ij = s_bi[qi][j];
            int rk = 0;
            for (int k = 0; k < cn; ++k)
                rk += lex_lt(s_bd[qi][k], s_bi[qi][k], dj, ij) ? 1 : 0;
            if (rk < KNN) idx_out[(size_t)(qbase + qq) * KNN + rk] = ij;
        }
    }
}

// ---------------- Kernel 2: MFMA agg — one wave per point, hi/lo bf16 (r11-proven) ----
#define MIDP 132   // s_mid leading-dim pad: 128 -> 132 breaks bank-aligned row stride
__global__ __launch_bounds__(256) void agg_kernel(
    const float* __restrict__ pts,
    const float* __restrict__ feat,
    const float* __restrict__ w_geom,
    const float* __restrict__ g1, const float* __restrict__ b1,
    const float* __restrict__ m1, const float* __restrict__ v1,
    const float* __restrict__ w_sem,
    const float* __restrict__ g2, const float* __restrict__ b2,
    const float* __restrict__ m2, const float* __restrict__ v2,
    const float* __restrict__ w_fuse,
    const float* __restrict__ g3, const float* __restrict__ b3,
    const float* __restrict__ m3, const float* __restrict__ v3,
    const int* __restrict__ knn_idx,
    float* __restrict__ outp) {

    __shared__ alignas(16) unsigned short s_wsemB[8192];    // 16 frags x 64 lanes x 8 bf16
    __shared__ alignas(16) unsigned short s_wfuseB[8192];
    __shared__ float s_wg[6][64];
    __shared__ float s_s1[64], s_b1[64], s_s2[64], s_b2[64], s_s3[64], s_b3[64];
    __shared__ alignas(16) float s_mid[4][16][MIDP];
    __shared__ float s_pm[4][4][64];
    __shared__ alignas(16) float s_ctrf[4][64];
    __shared__ float s_gd[4][16][4];
    __shared__ int   s_nidx[4][16];
    __shared__ float s_ctrp[4][4];

    const int tid = threadIdx.x;
    const int w = tid >> 6, lane = tid & 63;
    const int r = lane & 15, qd = lane >> 4;

    for (int e = tid; e < 1024; e += 256) {          // e = (kc*4+n0)*64 + ln
        const int ln = e & 63;
        const int o = ((e >> 6) & 3) * 16 + (ln & 15);
        const int c = (e >> 8) * 32 + (ln >> 4) * 8;
        unsigned short ts[8], tf[8];
#pragma unroll
        for (int j = 0; j < 8; ++j) {
            ts[j] = f2bf(w_sem [o * 128 + c + j]);
            tf[j] = f2bf(w_fuse[o * 128 + c + j]);
        }
        *(uint4*)&s_wsemB [e * 8] = *(uint4*)ts;
        *(uint4*)&s_wfuseB[e * 8] = *(uint4*)tf;
    }
    for (int e = tid; e < 384; e += 256) {
        const int c = e >> 6, o = e & 63;
        s_wg[c][o] = w_geom[o * 6 + c];
    }
    if (tid < 64) {
        float s;
        s = g1[tid] / sqrtf(v1[tid] + 1e-5f);
        s_s1[tid] = s; s_b1[tid] = b1[tid] - m1[tid] * s;
        s = g2[tid] / sqrtf(v2[tid] + 1e-5f);
        s_s2[tid] = s; s_b2[tid] = b2[tid] - m2[tid] * s;
        s = g3[tid] / sqrtf(v3[tid] + 1e-5f);
        s_s3[tid] = s; s_b3[tid] = b3[tid] - m3[tid] * s;
    }
    __syncthreads();

    const f32x4 zero = {0.f, 0.f, 0.f, 0.f};

    for (int i = 0; i < 4; ++i) {
        const int pv = blockIdx.x * 16 + w * 4 + i;
        const int b = pv >> 13, n = pv & (NPTS - 1);
        const long pbase = (long)b * NPTS + n;

        if (lane < 16) s_nidx[w][lane] = knn_idx[pbase * KNN + lane];
        s_ctrf[w][lane] = feat[pbase * CH + lane];
        if (lane < 3) s_ctrp[w][lane] = pts[pbase * 3 + lane];
        __syncthreads();                                       // B1

        if (lane < 16) {
            const long nb = (long)b * NPTS + s_nidx[w][lane];
            s_gd[w][lane][0] = pts[nb * 3 + 0] - s_ctrp[w][0];
            s_gd[w][lane][1] = pts[nb * 3 + 1] - s_ctrp[w][1];
            s_gd[w][lane][2] = pts[nb * 3 + 2] - s_ctrp[w][2];
        }

        bf16x8 ah[4], al[4];
        {
            float xs[8];
#pragma unroll
            for (int kc = 0; kc < 2; ++kc) {
#pragma unroll
                for (int j = 0; j < 8; ++j) xs[j] = s_ctrf[w][kc * 32 + qd * 8 + j];
                split8(xs, ah[kc], al[kc]);
            }
            const long nb = (long)b * NPTS + s_nidx[w][r];
            const float* fp = feat + nb * CH;
#pragma unroll
            for (int kc = 0; kc < 2; ++kc) {
                const int base = kc * 32 + qd * 8;
                const float4 v0 = *(const float4*)(fp + base);
                const float4 v1 = *(const float4*)(fp + base + 4);
                xs[0] = v0.x - s_ctrf[w][base + 0];
                xs[1] = v0.y - s_ctrf[w][base + 1];
                xs[2] = v0.z - s_ctrf[w][base + 2];
                xs[3] = v0.w - s_ctrf[w][base + 3];
                xs[4] = v1.x - s_ctrf[w][base + 4];
                xs[5] = v1.y - s_ctrf[w][base + 5];
                xs[6] = v1.z - s_ctrf[w][base + 6];
                xs[7] = v1.w - s_ctrf[w][base + 7];
                split8(xs, ah[2 + kc], al[2 + kc]);
            }
        }
        f32x4 acc[4] = {zero, zero, zero, zero};
#pragma unroll
        for (int kc = 0; kc < 4; ++kc) {
#pragma unroll
            for (int n0 = 0; n0 < 4; ++n0) {
                const bf16x8 bw = *(const bf16x8*)&s_wsemB[((kc * 4 + n0) * 64 + lane) * 8];
                acc[n0] = __builtin_amdgcn_mfma_f32_16x16x32_bf16(ah[kc], bw, acc[n0], 0, 0, 0);
                acc[n0] = __builtin_amdgcn_mfma_f32_16x16x32_bf16(al[kc], bw, acc[n0], 0, 0, 0);
            }
        }
#pragma unroll
        for (int n0 = 0; n0 < 4; ++n0) {
            const int nn = n0 * 16 + r;
            const float sv = s_s2[nn], bv = s_b2[nn];
#pragma unroll
            for (int reg = 0; reg < 4; ++reg) {
                s_mid[w][qd * 4 + reg][64 + nn] = fmaxf(fmaf(acc[n0][reg], sv, bv), 0.f);
            }
        }
        __syncthreads();                                       // B2 (s_gd ready)

        {
            const int o = lane;
            float cg = s_ctrp[w][0] * s_wg[0][o];
            cg = fmaf(s_ctrp[w][1], s_wg[1][o], cg);
            cg = fmaf(s_ctrp[w][2], s_wg[2][o], cg);
            const float s1o = s_s1[o], b1o = s_b1[o];
#pragma unroll
            for (int r2 = 0; r2 < 16; ++r2) {
                float g = cg;
                g = fmaf(s_gd[w][r2][0], s_wg[3][o], g);
                g = fmaf(s_gd[w][r2][1], s_wg[4][o], g);
                g = fmaf(s_gd[w][r2][2], s_wg[5][o], g);
                s_mid[w][r2][o] = fmaxf(fmaf(g, s1o, b1o), 0.f);
            }
        }
        __syncthreads();                                       // B3 (mid complete)

        bf16x8 fh[4], fl[4];
        {
            float xs[8];
#pragma unroll
            for (int kc = 0; kc < 4; ++kc) {
                const float* mp = &s_mid[w][r][kc * 32 + qd * 8];
#pragma unroll
                for (int j = 0; j < 8; ++j) xs[j] = mp[j];
                split8(xs, fh[kc], fl[kc]);
            }
        }
        f32x4 acc2[4] = {zero, zero, zero, zero};
#pragma unroll
        for (int kc = 0; kc < 4; ++kc) {
#pragma unroll
            for (int n0 = 0; n0 < 4; ++n0) {
                const bf16x8 bw = *(const bf16x8*)&s_wfuseB[((kc * 4 + n0) * 64 + lane) * 8];
                acc2[n0] = __builtin_amdgcn_mfma_f32_16x16x32_bf16(fh[kc], bw, acc2[n0], 0, 0, 0);
                acc2[n0] = __builtin_amdgcn_mfma_f32_16x16x32_bf16(fl[kc], bw, acc2[n0], 0, 0, 0);
            }
        }
#pragma unroll
        for (int n0 = 0; n0 < 4; ++n0) {
            const int nn = n0 * 16 + r;
            const float sv = s_s3[nn], bv = s_b3[nn];
            float mx = 0.f;   // relu outputs >= 0
#pragma unroll
            for (int reg = 0; reg < 4; ++reg)
                mx = fmaxf(mx, fmaxf(fmaf(acc2[n0][reg], sv, bv), 0.f));
            s_pm[w][qd][nn] = mx;
        }
        __syncthreads();                                       // B4
        {
            const int o = lane;
            const float rv = fmaxf(fmaxf(s_pm[w][0][o], s_pm[w][1][o]),
                                   fmaxf(s_pm[w][2][o], s_pm[w][3][o]));
            outp[pbase * CH + o] = rv;
        }
        __syncthreads();                                       // B5 (WAR across iters)
    }
}

extern "C" void kernel_launch(void* const* d_in, const int* in_sizes, int n_in,
                              void* d_out, int out_size, void* d_ws, size_t ws_size,
                              hipStream_t stream) {
    (void)in_sizes; (void)n_in; (void)out_size; (void)ws_size;
    const float* pts    = (const float*)d_in[0];
    const float* feat   = (const float*)d_in[1];
    const float* w_geom = (const float*)d_in[2];
    const float* g1     = (const float*)d_in[3];
    const float* b1     = (const float*)d_in[4];
    const float* m1     = (const float*)d_in[5];
    const float* v1     = (const float*)d_in[6];
    const float* w_sem  = (const float*)d_in[7];
    const float* g2     = (const float*)d_in[8];
    const float* b2     = (const float*)d_in[9];
    const float* m2     = (const float*)d_in[10];
    const float* v2     = (const float*)d_in[11];
    const float* w_fuse = (const float*)d_in[12];
    const float* g3     = (const float*)d_in[13];
    const float* b3     = (const float*)d_in[14];
    const float* m3     = (const float*)d_in[15];
    const float* v3     = (const float*)d_in[16];

    int*    idx_final = (int*)d_ws;                             // 2 MB @ 0
    float4* pts4      = (float4*)((char*)d_ws + (4ull << 20));  // 512 KB @ 4MB

    pack_kernel<<<dim3(NB * NPTS / 256), dim3(256), 0, stream>>>(pts, pts4);
    knn_wave_kernel<<<dim3(NB * NPTS / 16), dim3(256), 0, stream>>>(pts4, idx_final);

    agg_kernel<<<dim3(2048), dim3(256), 0, stream>>>(
        pts, feat, w_geom, g1, b1, m1, v1, w_sem, g2, b2, m2, v2,
        w_fuse, g3, b3, m3, v3, idx_final, (float*)d_out);
}